// Round 7
// baseline (217.749 us; speedup 1.0000x reference)
//
#include <hip/hip_runtime.h>
#include <hip/hip_fp16.h>
#include <math.h>

// CapsuleLayer dynamic routing, fp32, MI355X (gfx950).
// B=64, IN_CAPS=2048, IN_DIM=8, OUT_CAPS=32, OUT_DIM=16, 3 routing iters.
//
// b_ij after r updates = u_hat_i . (v0+...+v_{r-1}) (b starts at 0) -> no
// u_hat materialization; each pass recomputes it from W via LDS staging.
//
// R6 post-mortem: 46 us/pass, VALU 33%, occupancy 9.8%, HBM 17% -- latency/
// barrier-bound at 2 blocks/CU (grid 512). Also: W is 33.5 MB (not 8!), so
// BG=2 is the right W-traffic choice (67 MB/pass via L2/L3).
// R7:
//  * IPB 8->4: ISTR=512, grid 1024 -> 3 blocks/CU resident, 12 waves/CU.
//  * fp16 partials: 512 stripes x 32768 halves = 33.5 MB (same bytes as R6),
//    error ~3e-5 << 9.6e-4 threshold. Reduce reads halve.
//  * x staged once in prologue (out of the per-i barrier path).
//  * Keep: NB=8 frag reuse, lb(256,1) (VGPR 160, frags live), DPP softmax,
//    dense full-line nontemporal epilogue.

#define IC 2048
#define OC 32
#define OD 16
#define B_N 64
#define S_ELEMS (B_N * OC * OD)   // 32768
#define IPB 4                     // i per block
#define ISTR (IC / IPB)           // 512 partial slots
#define BPB 32                    // b per block
#define BG  (B_N / BPB)           // 2
#define NB  8                     // b per wave

typedef unsigned short us8 __attribute__((ext_vector_type(8)));

// DPP rotate-add within 16-lane rows: ror 8,4,2,1 leaves the row-sum in
// every lane of the row. VALU-pipe, no LDS.
template <int CTRL>
__device__ __forceinline__ float dpp_add(float v) {
    int r = __builtin_amdgcn_update_dpp(0, __float_as_int(v), CTRL, 0xf, 0xf, true);
    return v + __int_as_float(r);
}

// Lane map: o = lane&31, jh = lane>>5 (j = jh*8+jj), chunk c = (o<<1)|jh.
// Wave w owns b's bq..bq+7 (disjoint across waves).
// LDS W tile (per parity): WS[(dh*8+jj)*65 + c] -> fragment reads for fixed
// (dh,jj) are 64 contiguous float4 across lanes (bank-balanced); the 65
// stride spreads staging-write banks.

template <int FIRST>
__launch_bounds__(256, 1)
__global__ void caps_pass(const float* __restrict__ Wg,
                          const float* __restrict__ xg,
                          const float* __restrict__ vs,
                          __half* __restrict__ part)
{
    __shared__ float4 WS[2][16 * 65];   // 33.3 KB (epilogue overlays this)
    __shared__ float4 XS[IPB][64];      // 4 KB: x for all 4 i's, staged once
    float* accred = (float*)WS;         // epilogue: 16 b x 520 floats

    const int tid  = threadIdx.x;
    const int lane = tid & 63;
    const int w    = tid >> 6;
    const int o    = lane & 31;
    const int jh   = lane >> 5;
    const int c    = (o << 1) | jh;

    const int is   = blockIdx.x & (ISTR - 1);  // same-is pair 512 apart
    const int bg   = blockIdx.x >> 9;          // 0..1
    const int bblk = bg * BPB;
    const int bq   = bblk + w * NB;            // wave's first b

    const float4* wq = (const float4*)Wg;
    const float4* xq = (const float4*)xg;
    const int i0 = is * IPB;

    // v-sum fragments: fp32 registers, loaded once per wave (64 VGPRs)
    float4 va[NB], vb[NB];
    if (!FIRST) {
#pragma unroll
        for (int n = 0; n < NB; ++n) {
            const float4* vp = (const float4*)(vs + (size_t)(bq + n) * 512 + o * 16 + jh * 8);
            va[n] = vp[0];
            vb[n] = vp[1];
        }
    }

    float acc[NB][8];
#pragma unroll
    for (int n = 0; n < NB; ++n)
#pragma unroll
        for (int jj = 0; jj < 8; ++jj) acc[n][jj] = 0.0f;

    // ---- prologue: stage W tile 0 (parity 0) + ALL x (4 KB, once)
    {
        const size_t base = (size_t)i0 * 1024;
#pragma unroll
        for (int q = 0; q < 4; ++q) {
            const int G = q * 256 + tid;                 // quad index in tile
            const float4 val = wq[base + G];
            const int oo = G >> 5, j = (G >> 1) & 15, dh = G & 1;
            WS[0][((dh << 3) | (j & 7)) * 65 + ((oo << 1) | (j >> 3))] = val;
        }
        // XS[il][b*2+half] <- x[bblk+b][i0+il][half]; b=tid>>3, il=(tid>>1)&3
        {
            const int bl = tid >> 3, il = (tid >> 1) & 3, hf = tid & 1;
            XS[il][bl * 2 + hf] = xq[((size_t)(bblk + bl) * IC + i0 + il) * 2 + hf];
        }
    }

    for (int il = 0; il < IPB; ++il) {
        const int p = il & 1;
        __syncthreads();   // stage(il) visible; all waves done reading p^1

        // issue next W tile's global loads (latency hidden under compute)
        float4 g0 = {}, g1 = {}, g2 = {}, g3 = {};
        const bool more = (il + 1 < IPB);
        if (more) {
            const size_t base = (size_t)(i0 + il + 1) * 1024;
            g0 = wq[base + 0 * 256 + tid];
            g1 = wq[base + 1 * 256 + tid];
            g2 = wq[base + 2 * 256 + tid];
            g3 = wq[base + 3 * 256 + tid];
        }

        // W fragment -> 64 VGPRs (16 bank-balanced ds_read_b128), held across
        // the whole n-loop (lb(256,1) gives the register budget for this)
        float4 fr0[8], fr1[8];
#pragma unroll
        for (int jj = 0; jj < 8; ++jj) {
            fr0[jj] = WS[p][jj * 65 + c];
            fr1[jj] = WS[p][(8 + jj) * 65 + c];
        }

#pragma unroll
        for (int n = 0; n < NB; ++n) {
            const float4 xa = XS[il][(w * NB + n) * 2];       // broadcast reads
            const float4 xb = XS[il][(w * NB + n) * 2 + 1];

            float u[8];
#pragma unroll
            for (int jj = 0; jj < 8; ++jj) {
                float t = fr0[jj].x * xa.x;
                t = fmaf(fr0[jj].y, xa.y, t);
                t = fmaf(fr0[jj].z, xa.z, t);
                t = fmaf(fr0[jj].w, xa.w, t);
                t = fmaf(fr1[jj].x, xb.x, t);
                t = fmaf(fr1[jj].y, xb.y, t);
                t = fmaf(fr1[jj].z, xb.z, t);
                t = fmaf(fr1[jj].w, xb.w, t);
                u[jj] = t;
            }

            float cc;
            if (FIRST) {
                cc = 1.0f;   // softmax(0)=1/32 folded into epilogue scale
            } else {
                float bp = u[0] * va[n].x;
                bp = fmaf(u[1], va[n].y, bp);
                bp = fmaf(u[2], va[n].z, bp);
                bp = fmaf(u[3], va[n].w, bp);
                bp = fmaf(u[4], vb[n].x, bp);
                bp = fmaf(u[5], vb[n].y, bp);
                bp = fmaf(u[6], vb[n].z, bp);
                bp = fmaf(u[7], vb[n].w, bp);
                bp += __shfl_xor(bp, 32);          // combine j-halves
                const float e = __expf(bp);        // logits tiny; no max needed
                float se = e;
                se = dpp_add<0x128>(se);           // row_ror:8
                se = dpp_add<0x124>(se);           // row_ror:4
                se = dpp_add<0x122>(se);           // row_ror:2
                se = dpp_add<0x121>(se);           // row_ror:1
                se += __shfl_xor(se, 16);          // combine the two 16-rows
                cc = e * __builtin_amdgcn_rcpf(se);
            }
#pragma unroll
            for (int jj = 0; jj < 8; ++jj)
                acc[n][jj] = fmaf(cc, u[jj], acc[n][jj]);
        }

        // drain staged tile into the other parity (safe: top barrier of this
        // iteration guaranteed everyone finished reading p^1)
        if (more) {
            auto put = [&](int G, float4 val) {
                const int oo = G >> 5, j = (G >> 1) & 15, dh = G & 1;
                WS[p ^ 1][((dh << 3) | (j & 7)) * 65 + ((oo << 1) | (j >> 3))] = val;
            };
            put(0 * 256 + tid, g0);
            put(1 * 256 + tid, g1);
            put(2 * 256 + tid, g2);
            put(3 * 256 + tid, g3);
        }
    }

    // ---- epilogue: dense full-line fp16 stores via LDS, 2 phases of 16 b.
    const float scale = FIRST ? (1.0f / 32.0f) : 1.0f;
#pragma unroll
    for (int t = 0; t < 2; ++t) {
        __syncthreads();   // previous phase / main-loop reads complete
        if ((w >> 1) == t) {
            const int bl0 = (w & 1) * NB;
#pragma unroll
            for (int n = 0; n < NB; ++n)
#pragma unroll
                for (int jj = 0; jj < 8; ++jj)
                    accred[(bl0 + n) * 520 + jj * 64 + c] = acc[n][jj] * scale;
        }
        __syncthreads();
        // store 16 b x 512 = 8192 halves; unit = 8 consecutive j (16 B)
        __half* dstbase = part + (size_t)is * S_ELEMS + (size_t)(bblk + t * 16) * 512;
#pragma unroll
        for (int k2 = 0; k2 < 4; ++k2) {
            const int q   = k2 * 256 + tid;      // 0..1023 half8-unit
            const int bl  = q >> 6;
            const int oo  = (q >> 1) & 31;
            const int j0h = q & 1;               // j0 = j0h*8
            const int cb  = (oo << 1) | j0h;
            const float* src = accred + bl * 520 + cb;
            us8 hv;
#pragma unroll
            for (int k = 0; k < 8; ++k)
                hv[k] = __half_as_ushort(__float2half(src[k * 64]));
            __builtin_nontemporal_store(hv, (us8*)(dstbase + q * 8));
        }
    }
}

// Fused 512-way partial reduction + squash. Block: 128 e's (64 half2 cols),
// 4 waves x 128 k-slices, LDS combine, wave 0 squashes + stores float2.
// MODE 0: vsum = v   MODE 1: vsum += v   MODE 2: out = v
template <int MODE>
__global__ void caps_reduce(const __half* __restrict__ part,
                            float* __restrict__ vsum,
                            float* __restrict__ out)
{
    __shared__ float2 red[4][64];
    const int tid  = threadIdx.x;
    const int lane = tid & 63;
    const int ks   = tid >> 6;                       // 0..3
    const int e2   = blockIdx.x * 64 + lane;         // half2 column
    const unsigned* p32 = (const unsigned*)part;

    float sx = 0.0f, sy = 0.0f;
#pragma unroll 8
    for (int m = 0; m < 128; ++m) {
        const unsigned u =
            __builtin_nontemporal_load(p32 + (size_t)(ks * 128 + m) * (S_ELEMS / 2) + e2);
        const __half2 h = __builtin_bit_cast(__half2, u);
        const float2 f = __half22float2(h);
        sx += f.x;
        sy += f.y;
    }
    red[ks][lane] = make_float2(sx, sy);
    __syncthreads();
    if (tid < 64) {
        float2 a = red[0][lane], b2 = red[1][lane], c2 = red[2][lane], d2 = red[3][lane];
        const float ex = a.x + b2.x + c2.x + d2.x;
        const float ey = a.y + b2.y + c2.y + d2.y;
        // ||s||^2 over 16 j's = 8 lanes x 2 each (lane bits 0..2 = j-pair)
        float s2 = ex * ex + ey * ey;
        s2 += __shfl_xor(s2, 1);
        s2 += __shfl_xor(s2, 2);
        s2 += __shfl_xor(s2, 4);
        const float m = s2 / ((1.0f + s2) * sqrtf(s2 + 1e-9f));
        const float vx = ex * m, vy = ey * m;
        if (MODE == 2) {
            ((float2*)out)[e2] = make_float2(vx, vy);
        } else {
            float2 nv;
            if (MODE == 0) nv = make_float2(vx, vy);
            else {
                float2 old = ((float2*)vsum)[e2];
                nv = make_float2(old.x + vx, old.y + vy);
            }
            ((float2*)vsum)[e2] = nv;
        }
    }
}

extern "C" void kernel_launch(void* const* d_in, const int* in_sizes, int n_in,
                              void* d_out, int out_size, void* d_ws, size_t ws_size,
                              hipStream_t stream)
{
    const float* x = (const float*)d_in[0];   // [64, 2048, 8]
    const float* W = (const float*)d_in[1];   // [1, 2048, 32, 16, 8]
    float* out = (float*)d_out;               // [64, 32, 16]

    __half* part = (__half*)d_ws;                      // 512 x 32768 x 2 B = 33.5 MB
    float*  vsum = (float*)(part + (size_t)ISTR * S_ELEMS);  // 32768 floats

    const dim3 g(BG * ISTR);        // 1024 blocks
    const dim3 b(256);
    const dim3 rg(S_ELEMS / 128);   // 256 blocks

    caps_pass<1><<<g, b, 0, stream>>>(W, x, nullptr, part);
    caps_reduce<0><<<rg, b, 0, stream>>>(part, vsum, out);   // vsum = v0
    caps_pass<0><<<g, b, 0, stream>>>(W, x, vsum, part);
    caps_reduce<1><<<rg, b, 0, stream>>>(part, vsum, out);   // vsum = v0+v1
    caps_pass<0><<<g, b, 0, stream>>>(W, x, vsum, part);
    caps_reduce<2><<<rg, b, 0, stream>>>(part, vsum, out);   // out = v2
}